// Round 2
// baseline (153.977 us; speedup 1.0000x reference)
//
#include <hip/hip_runtime.h>

#define LOG2E 1.4426950408889634f
#define NEGBIG -3.0e38f

typedef float  f32x4  __attribute__((ext_vector_type(4)));
typedef float  f32x2  __attribute__((ext_vector_type(2)));
typedef short  bf16x8 __attribute__((ext_vector_type(8)));
typedef unsigned short u16x4 __attribute__((ext_vector_type(4)));
typedef int    i32x4  __attribute__((ext_vector_type(4)));
typedef int    i32x2  __attribute__((ext_vector_type(2)));

__device__ __forceinline__ unsigned short f2bf(float f) {
  union { float f; unsigned u; } v; v.f = f;
  unsigned r = v.u + 0x7FFFu + ((v.u >> 16) & 1u);
  return (unsigned short)(r >> 16);
}

__device__ __forceinline__ bf16x8 load_cvt8(const float* p) {
  f32x4 a = *(const f32x4*)p;
  f32x4 b = *(const f32x4*)(p + 4);
  bf16x8 r;
  r[0]=(short)f2bf(a[0]); r[1]=(short)f2bf(a[1]); r[2]=(short)f2bf(a[2]); r[3]=(short)f2bf(a[3]);
  r[4]=(short)f2bf(b[0]); r[5]=(short)f2bf(b[1]); r[6]=(short)f2bf(b[2]); r[7]=(short)f2bf(b[3]);
  return r;
}

// ---------------------------------------------------------------------------
// Kernel 1: QKV projection (unchanged, known-good).
// mode 0: Q (swapped C^T, prescaled log2e/sqrt(32)) -> Q[B][H][N][32] bf16
// mode 1: K (swapped C^T)                           -> K[B][H][N][32] bf16
// mode 2: V (normal)                                -> Vt[B][H][32][N] bf16
// ---------------------------------------------------------------------------
__global__ __launch_bounds__(256) void qkv_kernel(
    const float* __restrict__ x,
    const float* __restrict__ wq, const float* __restrict__ wk, const float* __restrict__ wv,
    unsigned short* __restrict__ Qo, unsigned short* __restrict__ Ko,
    unsigned short* __restrict__ Vto)
{
  const int mode = blockIdx.y;
  const int n0   = blockIdx.x * 64;
  const int b    = n0 >> 11;
  const int nl0  = n0 & 2047;
  const int wave = threadIdx.x >> 6;
  const int lane = threadIdx.x & 63;
  const int li = lane & 15, qt = lane >> 4;

  f32x4 acc[4][4];
#pragma unroll
  for (int i = 0; i < 4; i++)
#pragma unroll
    for (int j = 0; j < 4; j++) acc[i][j] = (f32x4)0.0f;

  if (mode < 2) {
    const float* w = mode ? wk : wq;
    unsigned short* out = mode ? Ko : Qo;
    const float osc = mode ? 1.0f : (1.4426950408889634f / 5.656854249492381f);
#pragma unroll
    for (int ks = 0; ks < 8; ks++) {
      bf16x8 af[4], bfr[4];
#pragma unroll
      for (int dm = 0; dm < 4; dm++)
        af[dm] = load_cvt8(w + (size_t)(wave*64 + dm*16 + li)*256 + ks*32 + qt*8);
#pragma unroll
      for (int nf = 0; nf < 4; nf++)
        bfr[nf] = load_cvt8(x + (size_t)(n0 + nf*16 + li)*256 + ks*32 + qt*8);
#pragma unroll
      for (int dm = 0; dm < 4; dm++)
#pragma unroll
        for (int nf = 0; nf < 4; nf++)
          acc[dm][nf] = __builtin_amdgcn_mfma_f32_16x16x32_bf16(af[dm], bfr[nf], acc[dm][nf], 0, 0, 0);
    }
#pragma unroll
    for (int dm = 0; dm < 4; dm++) {
      const int dbase = wave*64 + dm*16 + qt*4;
      const int h = dbase >> 5, dk = dbase & 31;
#pragma unroll
      for (int nf = 0; nf < 4; nf++) {
        const int nl = nl0 + nf*16 + li;
        u16x4 o;
#pragma unroll
        for (int r = 0; r < 4; r++) o[r] = f2bf(acc[dm][nf][r] * osc);
        *(u16x4*)(out + ((size_t)(b*8 + h)*2048 + nl)*32 + dk) = o;
      }
    }
  } else {
#pragma unroll
    for (int ks = 0; ks < 8; ks++) {
      bf16x8 af[4], bfr[4];
#pragma unroll
      for (int nm = 0; nm < 4; nm++)
        af[nm] = load_cvt8(x + (size_t)(n0 + nm*16 + li)*256 + ks*32 + qt*8);
#pragma unroll
      for (int df = 0; df < 4; df++)
        bfr[df] = load_cvt8(wv + (size_t)(wave*64 + df*16 + li)*256 + ks*32 + qt*8);
#pragma unroll
      for (int nm = 0; nm < 4; nm++)
#pragma unroll
        for (int df = 0; df < 4; df++)
          acc[nm][df] = __builtin_amdgcn_mfma_f32_16x16x32_bf16(af[nm], bfr[df], acc[nm][df], 0, 0, 0);
    }
#pragma unroll
    for (int nm = 0; nm < 4; nm++) {
      const int nl = nl0 + nm*16 + qt*4;
#pragma unroll
      for (int df = 0; df < 4; df++) {
        const int d = wave*64 + df*16 + li;
        const int h = d >> 5, dk = d & 31;
        u16x4 o;
#pragma unroll
        for (int r = 0; r < 4; r++) o[r] = f2bf(acc[nm][df][r]);
        *(u16x4*)(Vto + ((size_t)(b*8 + h)*32 + dk)*2048 + nl) = o;
      }
    }
  }
}

// ---------------------------------------------------------------------------
// Kernel 2: fused flash attention, q-tile 16. Grid 512 (2 blocks/CU), 8 waves
// = 8 heads per block. edge+mask staged once (LDS, double-buffered, bank-
// swizzled) in MFMA-C order, fed as the QK^T C-operand. S^T = K*Q^T so the
// softmax state is per-lane. PV: O^T = V^T * P^T via per-wave LDS P tile.
// ---------------------------------------------------------------------------
__global__ __launch_bounds__(512) void attn_kernel(
    const unsigned short* __restrict__ Qg,   // [B][H][N][32]
    const unsigned short* __restrict__ Kg,   // [B][H][N][32]
    const unsigned short* __restrict__ Vt,   // [B][H][32][N]
    const float* __restrict__ edge,          // [B][N][N]
    const int*   __restrict__ mask,          // [B][N][N]
    unsigned short* __restrict__ Og)         // [B][N][256]
{
  __shared__ float me_s[2][1024];            // 16q x 64k, MFMA-C frag order
  __shared__ unsigned short pb_s[8][1024];   // per-wave P (64k x 16q), B-frag order

  const int bid = blockIdx.x;
  // XCD swizzle: batch b pinned to XCD pair {2b,2b+1} for K/V L2 residency
  const int b  = (bid >> 1) & 3;
  const int qi = ((bid >> 3) << 1) | (bid & 1);
  const int q0 = qi * 16;
  const int tid  = threadIdx.x;
  const int wave = tid >> 6;                 // = head
  const int lane = tid & 63;
  const int li = lane & 15, qt = lane >> 4;
  const int h = wave;

  const unsigned short* qbase = Qg + ((size_t)(b*8 + h)*2048 + q0)*32;
  const unsigned short* kbase = Kg + ((size_t)(b*8 + h)*2048)*32;
  const unsigned short* vbase = Vt + ((size_t)(b*8 + h)*32)*2048;
  const float* ebase = edge + ((size_t)b*2048 + q0)*2048;
  const int*   mbase = mask + ((size_t)b*2048 + q0)*2048;

  const bf16x8 qf = *(const bf16x8*)(qbase + (size_t)li*32 + qt*8);

  // staging map: thread t -> (q = t>>5, keys 2*(t&31)..+1), f32x2/i32x2 loads
  const int sq = tid >> 5;
  const int sk = (tid & 31) * 2;
  // write idx (floats): cell = (key>>4)*64 + ((key>>2)&3)*16 + (q ^ ((key>>2)&7)), elem key&3
  const int widx = ((sk >> 4)*64 + ((sk >> 2) & 3)*16 + (sq ^ ((sk >> 2) & 7)))*4 + (sk & 3);
  // C-in read idx per frag sm (same swizzle: q-field XORed with (sm&1)*4|qt)
  int ridx[4];
#pragma unroll
  for (int sm = 0; sm < 4; sm++)
    ridx[sm] = (sm*64 + qt*16 + (li ^ (((sm & 1) << 2) | qt)))*4;

  { // stage tile 0
    f32x2 e2 = *(const f32x2*)(ebase + (size_t)sq*2048 + sk);
    i32x2 m2 = *(const i32x2*)(mbase + (size_t)sq*2048 + sk);
    f32x2 v;
    v[0] = m2[0] ? e2[0]*LOG2E : NEGBIG;
    v[1] = m2[1] ? e2[1]*LOG2E : NEGBIG;
    *(f32x2*)&me_s[0][widx] = v;
  }
  __syncthreads();

  float m_run = NEGBIG, l_run = 0.f;
  f32x4 oacc[2];
  oacc[0] = (f32x4)0.0f; oacc[1] = (f32x4)0.0f;
  unsigned short* pw = &pb_s[wave][0];

  for (int kt = 0; kt < 32; ++kt) {
    const int cur = kt & 1;
    const int k0 = kt * 64;
    const bool do_stage = (kt + 1 < 32);

    f32x2 se2; i32x2 sm2;
    if (do_stage) {
      se2 = *(const f32x2*)(ebase + (size_t)sq*2048 + (k0 + 64) + sk);
      sm2 = *(const i32x2*)(mbase + (size_t)sq*2048 + (k0 + 64) + sk);
    }

    bf16x8 kf[4], vf[2][2];
#pragma unroll
    for (int sm = 0; sm < 4; sm++)
      kf[sm] = *(const bf16x8*)(kbase + (size_t)(k0 + sm*16 + li)*32 + qt*8);
#pragma unroll
    for (int dm = 0; dm < 2; dm++)
#pragma unroll
      for (int k2 = 0; k2 < 2; k2++)
        vf[dm][k2] = *(const bf16x8*)(vbase + (size_t)(dm*16 + li)*2048 + k0 + k2*32 + qt*8);

    // S^T = K * Q^T + me (me as MFMA C-in). row = key, col = q = li.
    f32x4 s[4];
#pragma unroll
    for (int sm = 0; sm < 4; sm++) {
      const f32x4 c = *(const f32x4*)&me_s[cur][ridx[sm]];
      s[sm] = __builtin_amdgcn_mfma_f32_16x16x32_bf16(kf[sm], qf, c, 0, 0, 0);
    }

    // online softmax over 64-key tile (per q column = per lane li)
    float mx = s[0][0];
#pragma unroll
    for (int sm = 0; sm < 4; sm++)
#pragma unroll
      for (int r = 0; r < 4; r++) mx = fmaxf(mx, s[sm][r]);
    mx = fmaxf(mx, __shfl_xor(mx, 16));
    mx = fmaxf(mx, __shfl_xor(mx, 32));
    const float mnew = fmaxf(m_run, mx);
    const float scale = __builtin_amdgcn_exp2f(m_run - mnew);
    m_run = mnew;
    float rs = 0.f;
#pragma unroll
    for (int sm = 0; sm < 4; sm++)
#pragma unroll
      for (int r = 0; r < 4; r++) {
        const float p = __builtin_amdgcn_exp2f(s[sm][r] - mnew);
        s[sm][r] = p;
        rs += p;
      }
    rs += __shfl_xor(rs, 16);
    rs += __shfl_xor(rs, 32);
    l_run = l_run*scale + rs;
#pragma unroll
    for (int r = 0; r < 4; r++) { oacc[0][r] *= scale; oacc[1][r] *= scale; }

    // pack P -> per-wave LDS in PV-B-fragment order (bank-swizzled)
#pragma unroll
    for (int sm = 0; sm < 4; sm++) {
      u16x4 pk;
#pragma unroll
      for (int r = 0; r < 4; r++) pk[r] = f2bf(s[sm][r]);
      const int kgroup = sm*2 + (qt >> 1);
      const int liw = li ^ ((kgroup & 1) << 2);
      *(u16x4*)((char*)pw + (kgroup*16 + liw)*16 + (qt & 1)*8) = pk;
    }

    // PV: O^T += V^T * P^T
#pragma unroll
    for (int k2 = 0; k2 < 2; k2++) {
      const int fr = k2*4 + qt;
      const int lir = li ^ ((fr & 1) << 2);
      const bf16x8 pf = *(const bf16x8*)((char*)pw + (fr*16 + lir)*16);
#pragma unroll
      for (int dm = 0; dm < 2; dm++)
        oacc[dm] = __builtin_amdgcn_mfma_f32_16x16x32_bf16(vf[dm][k2], pf, oacc[dm], 0, 0, 0);
    }

    if (do_stage) {
      f32x2 v;
      v[0] = sm2[0] ? se2[0]*LOG2E : NEGBIG;
      v[1] = sm2[1] ? se2[1]*LOG2E : NEGBIG;
      *(f32x2*)&me_s[cur ^ 1][widx] = v;
    }
    __syncthreads();
  }

  const float rl = 1.0f / l_run;
#pragma unroll
  for (int dm = 0; dm < 2; dm++) {
    u16x4 o;
#pragma unroll
    for (int r = 0; r < 4; r++) o[r] = f2bf(oacc[dm][r] * rl);
    *(u16x4*)(Og + ((size_t)(b*2048 + q0 + li))*256 + h*32 + dm*16 + qt*4) = o;
  }
}

// ---------------------------------------------------------------------------
// Kernel 3: output projection (unchanged, known-good).
// ---------------------------------------------------------------------------
__global__ __launch_bounds__(256) void proj_kernel(
    const unsigned short* __restrict__ O,    // [8192][256] bf16
    const float* __restrict__ wo, const float* __restrict__ bo,
    float* __restrict__ Y)                   // [8192][256] f32
{
  const int n0   = blockIdx.x * 64;
  const int wave = threadIdx.x >> 6;
  const int lane = threadIdx.x & 63;
  const int li = lane & 15, qt = lane >> 4;

  f32x4 acc[4][4];
#pragma unroll
  for (int i = 0; i < 4; i++)
#pragma unroll
    for (int j = 0; j < 4; j++) acc[i][j] = (f32x4)0.0f;

#pragma unroll
  for (int ks = 0; ks < 8; ks++) {
    bf16x8 af[4], bfr[4];
#pragma unroll
    for (int dm = 0; dm < 4; dm++)
      af[dm] = load_cvt8(wo + (size_t)(wave*64 + dm*16 + li)*256 + ks*32 + qt*8);
#pragma unroll
    for (int nf = 0; nf < 4; nf++)
      bfr[nf] = *(const bf16x8*)(O + (size_t)(n0 + nf*16 + li)*256 + ks*32 + qt*8);
#pragma unroll
    for (int dm = 0; dm < 4; dm++)
#pragma unroll
      for (int nf = 0; nf < 4; nf++)
        acc[dm][nf] = __builtin_amdgcn_mfma_f32_16x16x32_bf16(af[dm], bfr[nf], acc[dm][nf], 0, 0, 0);
  }

#pragma unroll
  for (int dm = 0; dm < 4; dm++) {
    const int d0 = wave*64 + dm*16 + qt*4;
    const f32x4 bo4 = *(const f32x4*)(bo + d0);
#pragma unroll
    for (int nf = 0; nf < 4; nf++) {
      const int n = n0 + nf*16 + li;
      f32x4 y = acc[dm][nf] + bo4;
      *(f32x4*)(Y + (size_t)n*256 + d0) = y;
    }
  }
}

// ---------------------------------------------------------------------------
extern "C" void kernel_launch(void* const* d_in, const int* in_sizes, int n_in,
                              void* d_out, int out_size, void* d_ws, size_t ws_size,
                              hipStream_t stream) {
  const float* x  = (const float*)d_in[0];
  const float* ew = (const float*)d_in[1];
  const int*   mk = (const int*)d_in[2];
  const float* wq = (const float*)d_in[3];
  const float* wk = (const float*)d_in[4];
  const float* wv = (const float*)d_in[5];
  const float* wo = (const float*)d_in[6];
  const float* bo = (const float*)d_in[7];
  float* y = (float*)d_out;

  unsigned short* Q  = (unsigned short*)d_ws;       // [4][8][2048][32] bf16
  unsigned short* K  = Q  + 2097152;
  unsigned short* Vt = K  + 2097152;                // [4][8][32][2048] bf16
  unsigned short* O  = Vt + 2097152;                // [4][2048][256]  bf16

  qkv_kernel<<<dim3(128, 3), 256, 0, stream>>>(x, wq, wk, wv, Q, K, Vt);
  attn_kernel<<<512, 512, 0, stream>>>(Q, K, Vt, ew, mk, O);
  proj_kernel<<<128, 256, 0, stream>>>(O, wo, bo, y);
}

// Round 3
// 121.317 us; speedup vs baseline: 1.2692x; 1.2692x over previous
//
#include <hip/hip_runtime.h>

#define LOG2E 1.4426950408889634f
#define NEGBIG -3.0e38f

typedef float  f32x4  __attribute__((ext_vector_type(4)));
typedef float  f32x2  __attribute__((ext_vector_type(2)));
typedef short  bf16x8 __attribute__((ext_vector_type(8)));
typedef unsigned short u16x4 __attribute__((ext_vector_type(4)));
typedef int    i32x4  __attribute__((ext_vector_type(4)));
typedef int    i32x2  __attribute__((ext_vector_type(2)));

__device__ __forceinline__ unsigned short f2bf(float f) {
  union { float f; unsigned u; } v; v.f = f;
  unsigned r = v.u + 0x7FFFu + ((v.u >> 16) & 1u);
  return (unsigned short)(r >> 16);
}

__device__ __forceinline__ bf16x8 load_cvt8(const float* p) {
  f32x4 a = *(const f32x4*)p;
  f32x4 b = *(const f32x4*)(p + 4);
  bf16x8 r;
  r[0]=(short)f2bf(a[0]); r[1]=(short)f2bf(a[1]); r[2]=(short)f2bf(a[2]); r[3]=(short)f2bf(a[3]);
  r[4]=(short)f2bf(b[0]); r[5]=(short)f2bf(b[1]); r[6]=(short)f2bf(b[2]); r[7]=(short)f2bf(b[3]);
  return r;
}

// ---------------------------------------------------------------------------
// Kernel 1: QKV projection (unchanged, known-good).
// ---------------------------------------------------------------------------
__global__ __launch_bounds__(256) void qkv_kernel(
    const float* __restrict__ x,
    const float* __restrict__ wq, const float* __restrict__ wk, const float* __restrict__ wv,
    unsigned short* __restrict__ Qo, unsigned short* __restrict__ Ko,
    unsigned short* __restrict__ Vto)
{
  const int mode = blockIdx.y;
  const int n0   = blockIdx.x * 64;
  const int b    = n0 >> 11;
  const int nl0  = n0 & 2047;
  const int wave = threadIdx.x >> 6;
  const int lane = threadIdx.x & 63;
  const int li = lane & 15, qt = lane >> 4;

  f32x4 acc[4][4];
#pragma unroll
  for (int i = 0; i < 4; i++)
#pragma unroll
    for (int j = 0; j < 4; j++) acc[i][j] = (f32x4)0.0f;

  if (mode < 2) {
    const float* w = mode ? wk : wq;
    unsigned short* out = mode ? Ko : Qo;
    const float osc = mode ? 1.0f : (1.4426950408889634f / 5.656854249492381f);
#pragma unroll
    for (int ks = 0; ks < 8; ks++) {
      bf16x8 af[4], bfr[4];
#pragma unroll
      for (int dm = 0; dm < 4; dm++)
        af[dm] = load_cvt8(w + (size_t)(wave*64 + dm*16 + li)*256 + ks*32 + qt*8);
#pragma unroll
      for (int nf = 0; nf < 4; nf++)
        bfr[nf] = load_cvt8(x + (size_t)(n0 + nf*16 + li)*256 + ks*32 + qt*8);
#pragma unroll
      for (int dm = 0; dm < 4; dm++)
#pragma unroll
        for (int nf = 0; nf < 4; nf++)
          acc[dm][nf] = __builtin_amdgcn_mfma_f32_16x16x32_bf16(af[dm], bfr[nf], acc[dm][nf], 0, 0, 0);
    }
#pragma unroll
    for (int dm = 0; dm < 4; dm++) {
      const int dbase = wave*64 + dm*16 + qt*4;
      const int h = dbase >> 5, dk = dbase & 31;
#pragma unroll
      for (int nf = 0; nf < 4; nf++) {
        const int nl = nl0 + nf*16 + li;
        u16x4 o;
#pragma unroll
        for (int r = 0; r < 4; r++) o[r] = f2bf(acc[dm][nf][r] * osc);
        *(u16x4*)(out + ((size_t)(b*8 + h)*2048 + nl)*32 + dk) = o;
      }
    }
  } else {
#pragma unroll
    for (int ks = 0; ks < 8; ks++) {
      bf16x8 af[4], bfr[4];
#pragma unroll
      for (int nm = 0; nm < 4; nm++)
        af[nm] = load_cvt8(x + (size_t)(n0 + nm*16 + li)*256 + ks*32 + qt*8);
#pragma unroll
      for (int df = 0; df < 4; df++)
        bfr[df] = load_cvt8(wv + (size_t)(wave*64 + df*16 + li)*256 + ks*32 + qt*8);
#pragma unroll
      for (int nm = 0; nm < 4; nm++)
#pragma unroll
        for (int df = 0; df < 4; df++)
          acc[nm][df] = __builtin_amdgcn_mfma_f32_16x16x32_bf16(af[nm], bfr[df], acc[nm][df], 0, 0, 0);
    }
#pragma unroll
    for (int nm = 0; nm < 4; nm++) {
      const int nl = nl0 + nm*16 + qt*4;
#pragma unroll
      for (int df = 0; df < 4; df++) {
        const int d = wave*64 + df*16 + li;
        const int h = d >> 5, dk = d & 31;
        u16x4 o;
#pragma unroll
        for (int r = 0; r < 4; r++) o[r] = f2bf(acc[nm][df][r]);
        *(u16x4*)(Vto + ((size_t)(b*8 + h)*32 + dk)*2048 + nl) = o;
      }
    }
  }
}

// ---------------------------------------------------------------------------
// Kernel 2: fused flash attention, q-tile 32, k-tile 64, 8 waves = 8 heads.
// Software-pipelined: K(kt+1) + edge/mask(kt+1) prefetched into registers at
// top of iter kt; LDS me-tile double-buffered; barrier is lgkm-only (raw
// s_barrier) so prefetched global loads stay in flight across it.
// ---------------------------------------------------------------------------
__global__ __launch_bounds__(512, 2) void attn_kernel(
    const unsigned short* __restrict__ Qg,   // [B][H][N][32]
    const unsigned short* __restrict__ Kg,   // [B][H][N][32]
    const unsigned short* __restrict__ Vt,   // [B][H][32][N]
    const float* __restrict__ edge,          // [B][N][N]
    const int*   __restrict__ mask,          // [B][N][N]
    unsigned short* __restrict__ Og)         // [B][N][256]
{
  __shared__ __attribute__((aligned(16))) float me_s[2][2048];          // 32q x 64k, C-frag order
  __shared__ __attribute__((aligned(16))) unsigned short pb_s[8][2048]; // per-wave P, B-frag order

  const int bid = blockIdx.x;
  // XCD swizzle: batch b pinned to XCD pair {2b,2b+1}
  const int b  = (bid >> 1) & 3;
  const int qi = ((bid >> 3) << 1) | (bid & 1);   // 0..63
  const int q0 = qi * 32;
  const int tid  = threadIdx.x;
  const int wave = tid >> 6;                 // = head
  const int lane = tid & 63;
  const int li = lane & 15, qt = lane >> 4;
  const int h = wave;

  const unsigned short* qbase = Qg + ((size_t)(b*8 + h)*2048 + q0)*32;
  const unsigned short* kbase = Kg + ((size_t)(b*8 + h)*2048)*32;
  const unsigned short* vbase = Vt + ((size_t)(b*8 + h)*32)*2048;

  // staging map: thread t -> (q = t>>4, keys (t&15)*4 .. +3)
  const int q_s = tid >> 4;                  // 0..31
  const int k4  = (tid & 15) * 4;
  const float* eaddr = edge + ((size_t)b*2048 + q0 + q_s)*2048 + k4;
  const int*   maddr = mask + ((size_t)b*2048 + q0 + q_s)*2048 + k4;
  // me_s write index (floats): frag*256 + cell*4, XOR-swizzled
  const int qt_w   = (k4 >> 2) & 3;
  const int frag_w = (k4 >> 4)*2 + (q_s >> 4);
  const int cell_w = qt_w*16 + ((q_s & 15) ^ qt_w ^ (((q_s >> 4) & 1) << 2));
  const int widx   = frag_w*256 + cell_w*4;
  // me_s C-in read bases per q-frag sn
  int rb[2];
  rb[0] = (qt*16 + (li ^ qt)) * 4;
  rb[1] = (qt*16 + (li ^ qt ^ 4)) * 4;
  // P-tile halfword bases (per-wave region)
  unsigned short* pw = &pb_s[wave][0];
  const int pw_base = (qt >> 1)*256 + (li ^ ((qt >> 1) << 2))*8 + (qt & 1)*4;
  const int pr_base = qt*256 + (li ^ ((qt & 1) << 2))*8;

  bf16x8 qf[2];
  qf[0] = *(const bf16x8*)(qbase + (size_t)li*32 + qt*8);
  qf[1] = *(const bf16x8*)(qbase + (size_t)(16 + li)*32 + qt*8);

  { // stage tile 0 into me_s[0]
    f32x4 e4 = *(const f32x4*)eaddr;
    i32x4 m4 = *(const i32x4*)maddr;
    f32x4 v;
#pragma unroll
    for (int r = 0; r < 4; r++) v[r] = m4[r] ? e4[r]*LOG2E : NEGBIG;
    *(f32x4*)&me_s[0][widx] = v;
  }
  __syncthreads();

  // preload K tile 0
  bf16x8 kf_a[4], kf_b[4];
#pragma unroll
  for (int i = 0; i < 4; i++)
    kf_a[i] = *(const bf16x8*)(kbase + (size_t)(i*16 + li)*32 + qt*8);

  float m_run[2] = {NEGBIG, NEGBIG};
  float l_run[2] = {0.f, 0.f};
  f32x4 oacc[2][2];
#pragma unroll
  for (int i = 0; i < 2; i++)
#pragma unroll
    for (int j = 0; j < 2; j++) oacc[i][j] = (f32x4)0.0f;

#define ATTN_STEP(KT, CUR, KC, KN)                                            \
  {                                                                           \
    const int k0n = (((KT) + 1) & 31) * 64;                                   \
    const f32x4 se  = *(const f32x4*)(eaddr + k0n);                           \
    const i32x4 smi = *(const i32x4*)(maddr + k0n);                           \
    _Pragma("unroll")                                                         \
    for (int i = 0; i < 4; i++)                                               \
      KN[i] = *(const bf16x8*)(kbase + (size_t)(k0n + i*16 + li)*32 + qt*8);  \
    const int k0 = (KT) * 64;                                                 \
    const bf16x8 vf00 = *(const bf16x8*)(vbase + (size_t)li*2048      + k0      + qt*8); \
    const bf16x8 vf01 = *(const bf16x8*)(vbase + (size_t)li*2048      + k0 + 32 + qt*8); \
    const bf16x8 vf10 = *(const bf16x8*)(vbase + (size_t)(16+li)*2048 + k0      + qt*8); \
    const bf16x8 vf11 = *(const bf16x8*)(vbase + (size_t)(16+li)*2048 + k0 + 32 + qt*8); \
    f32x4 s[4][2];                                                            \
    _Pragma("unroll")                                                         \
    for (int sm = 0; sm < 4; sm++) {                                          \
      _Pragma("unroll")                                                       \
      for (int sn = 0; sn < 2; sn++) {                                        \
        const f32x4 c = *(const f32x4*)&me_s[CUR][(sm*2+sn)*256 + rb[sn]];    \
        s[sm][sn] = __builtin_amdgcn_mfma_f32_16x16x32_bf16(KC[sm], qf[sn], c, 0, 0, 0); \
      }                                                                       \
    }                                                                         \
    _Pragma("unroll")                                                         \
    for (int sn = 0; sn < 2; sn++) {                                          \
      float mx = s[0][sn][0];                                                 \
      _Pragma("unroll")                                                       \
      for (int sm = 0; sm < 4; sm++)                                          \
        _Pragma("unroll")                                                     \
        for (int r = 0; r < 4; r++) mx = fmaxf(mx, s[sm][sn][r]);             \
      mx = fmaxf(mx, __shfl_xor(mx, 16));                                     \
      mx = fmaxf(mx, __shfl_xor(mx, 32));                                     \
      const float mnew = fmaxf(m_run[sn], mx);                                \
      const float sc = __builtin_amdgcn_exp2f(m_run[sn] - mnew);              \
      m_run[sn] = mnew;                                                       \
      float rs = 0.f;                                                         \
      _Pragma("unroll")                                                       \
      for (int sm = 0; sm < 4; sm++)                                          \
        _Pragma("unroll")                                                     \
        for (int r = 0; r < 4; r++) {                                         \
          const float p = __builtin_amdgcn_exp2f(s[sm][sn][r] - mnew);        \
          s[sm][sn][r] = p;                                                   \
          rs += p;                                                            \
        }                                                                     \
      rs += __shfl_xor(rs, 16);                                               \
      rs += __shfl_xor(rs, 32);                                               \
      l_run[sn] = l_run[sn]*sc + rs;                                          \
      _Pragma("unroll")                                                       \
      for (int r = 0; r < 4; r++) { oacc[0][sn][r] *= sc; oacc[1][sn][r] *= sc; } \
    }                                                                         \
    _Pragma("unroll")                                                         \
    for (int sm = 0; sm < 4; sm++) {                                          \
      _Pragma("unroll")                                                       \
      for (int sn = 0; sn < 2; sn++) {                                        \
        u16x4 pk;                                                             \
        _Pragma("unroll")                                                     \
        for (int r = 0; r < 4; r++) pk[r] = f2bf(s[sm][sn][r]);               \
        *(u16x4*)(pw + pw_base + sm*512 + sn*128) = pk;                       \
      }                                                                       \
    }                                                                         \
    _Pragma("unroll")                                                         \
    for (int sn = 0; sn < 2; sn++) {                                          \
      _Pragma("unroll")                                                       \
      for (int k2 = 0; k2 < 2; k2++) {                                        \
        const bf16x8 pf = *(const bf16x8*)(pw + pr_base + k2*1024 + sn*128);  \
        oacc[0][sn] = __builtin_amdgcn_mfma_f32_16x16x32_bf16(                \
            (k2 ? vf01 : vf00), pf, oacc[0][sn], 0, 0, 0);                    \
        oacc[1][sn] = __builtin_amdgcn_mfma_f32_16x16x32_bf16(                \
            (k2 ? vf11 : vf10), pf, oacc[1][sn], 0, 0, 0);                    \
      }                                                                       \
    }                                                                         \
    f32x4 mev;                                                                \
    _Pragma("unroll")                                                         \
    for (int r = 0; r < 4; r++) mev[r] = smi[r] ? se[r]*LOG2E : NEGBIG;       \
    *(f32x4*)&me_s[(CUR) ^ 1][widx] = mev;                                    \
    asm volatile("s_waitcnt lgkmcnt(0)\n\ts_barrier" ::: "memory");           \
  }

  for (int kp = 0; kp < 16; ++kp) {
    ATTN_STEP(kp*2,     0, kf_a, kf_b)
    ATTN_STEP(kp*2 + 1, 1, kf_b, kf_a)
  }
#undef ATTN_STEP

#pragma unroll
  for (int sn = 0; sn < 2; sn++) {
    const float rl = 1.0f / l_run[sn];
#pragma unroll
    for (int dm = 0; dm < 2; dm++) {
      u16x4 o;
#pragma unroll
      for (int r = 0; r < 4; r++) o[r] = f2bf(oacc[dm][sn][r] * rl);
      *(u16x4*)(Og + ((size_t)(b*2048 + q0 + sn*16 + li))*256 + h*32 + dm*16 + qt*4) = o;
    }
  }
}

// ---------------------------------------------------------------------------
// Kernel 3: output projection (unchanged, known-good).
// ---------------------------------------------------------------------------
__global__ __launch_bounds__(256) void proj_kernel(
    const unsigned short* __restrict__ O,    // [8192][256] bf16
    const float* __restrict__ wo, const float* __restrict__ bo,
    float* __restrict__ Y)                   // [8192][256] f32
{
  const int n0   = blockIdx.x * 64;
  const int wave = threadIdx.x >> 6;
  const int lane = threadIdx.x & 63;
  const int li = lane & 15, qt = lane >> 4;

  f32x4 acc[4][4];
#pragma unroll
  for (int i = 0; i < 4; i++)
#pragma unroll
    for (int j = 0; j < 4; j++) acc[i][j] = (f32x4)0.0f;

#pragma unroll
  for (int ks = 0; ks < 8; ks++) {
    bf16x8 af[4], bfr[4];
#pragma unroll
    for (int dm = 0; dm < 4; dm++)
      af[dm] = load_cvt8(wo + (size_t)(wave*64 + dm*16 + li)*256 + ks*32 + qt*8);
#pragma unroll
    for (int nf = 0; nf < 4; nf++)
      bfr[nf] = *(const bf16x8*)(O + (size_t)(n0 + nf*16 + li)*256 + ks*32 + qt*8);
#pragma unroll
    for (int dm = 0; dm < 4; dm++)
#pragma unroll
      for (int nf = 0; nf < 4; nf++)
        acc[dm][nf] = __builtin_amdgcn_mfma_f32_16x16x32_bf16(af[dm], bfr[nf], acc[dm][nf], 0, 0, 0);
  }

#pragma unroll
  for (int dm = 0; dm < 4; dm++) {
    const int d0 = wave*64 + dm*16 + qt*4;
    const f32x4 bo4 = *(const f32x4*)(bo + d0);
#pragma unroll
    for (int nf = 0; nf < 4; nf++) {
      const int n = n0 + nf*16 + li;
      f32x4 y = acc[dm][nf] + bo4;
      *(f32x4*)(Y + (size_t)n*256 + d0) = y;
    }
  }
}

// ---------------------------------------------------------------------------
extern "C" void kernel_launch(void* const* d_in, const int* in_sizes, int n_in,
                              void* d_out, int out_size, void* d_ws, size_t ws_size,
                              hipStream_t stream) {
  const float* x  = (const float*)d_in[0];
  const float* ew = (const float*)d_in[1];
  const int*   mk = (const int*)d_in[2];
  const float* wq = (const float*)d_in[3];
  const float* wk = (const float*)d_in[4];
  const float* wv = (const float*)d_in[5];
  const float* wo = (const float*)d_in[6];
  const float* bo = (const float*)d_in[7];
  float* y = (float*)d_out;

  unsigned short* Q  = (unsigned short*)d_ws;       // [4][8][2048][32] bf16
  unsigned short* K  = Q  + 2097152;
  unsigned short* Vt = K  + 2097152;                // [4][8][32][2048] bf16
  unsigned short* O  = Vt + 2097152;                // [4][2048][256]  bf16

  qkv_kernel<<<dim3(128, 3), 256, 0, stream>>>(x, wq, wk, wv, Q, K, Vt);
  attn_kernel<<<256, 512, 0, stream>>>(Q, K, Vt, ew, mk, O);
  proj_kernel<<<128, 256, 0, stream>>>(O, wo, bo, y);
}